// Round 4
// baseline (526.473 us; speedup 1.0000x reference)
//
#include <hip/hip_runtime.h>
#include <hip/hip_bf16.h>
#include <cstdint>
#include <cstddef>

typedef __hip_bfloat16 bf16;
using f32x4  = __attribute__((ext_vector_type(4))) float;
using bf16x8 = __attribute__((ext_vector_type(8))) short;

#define DEVI __device__ __forceinline__

DEVI float b2f(unsigned short u) {
  union { float f; unsigned int i; } c; c.i = ((unsigned int)u) << 16; return c.f;
}

DEVI int reg3(int u) { return (u < 49) ? 0 : ((u < 53) ? 1 : 2); }

// ---------- fp32 -> bf16 weight conversion ----------
__global__ __launch_bounds__(256) void cvt_kernel(const float* __restrict__ src,
                                                  bf16* __restrict__ dst, int n)
{
  const int i = blockIdx.x * 256 + threadIdx.x;
  if (i < n) dst[i] = __float2bfloat16(src[i]);
}

// ---------- LayerNorm over C=192 (fp32 in, bf16 out), optional shift+window gather ----------
template<bool PERM>
__global__ __launch_bounds__(256) void ln_kernel(const float* __restrict__ x,
                                                 const float* __restrict__ gw,
                                                 const float* __restrict__ bw,
                                                 bf16* __restrict__ out,
                                                 int grow0)
{
  const int lane = threadIdx.x & 63;
  const int ridx = blockIdx.x * 4 + (threadIdx.x >> 6);
  size_t src;
  if (PERM) {
    const int g   = grow0 + ridx;
    const int wid = g / 49;
    const int nn  = g - wid * 49;
    const int b_  = wid >> 6, wim = wid & 63;
    const int wy  = wim >> 3, wx = wim & 7;
    const int ny  = nn / 7,  nx = nn - (nn / 7) * 7;
    int i = wy * 7 + ny + 3; if (i >= 56) i -= 56;   // shifted coord u reads x[(u+3)%56]
    int j = wx * 7 + nx + 3; if (j >= 56) j -= 56;
    src = (size_t)(b_ * 3136 + i * 56 + j);
  } else {
    src = (size_t)ridx;
  }
  const float* xr = x + src * 192;
  float v0 = xr[lane];
  float v1 = xr[lane + 64];
  float v2 = xr[lane + 128];
  float s = v0 + v1 + v2;
#pragma unroll
  for (int off = 32; off > 0; off >>= 1) s += __shfl_xor(s, off);
  const float mu = s * (1.0f / 192.0f);
  const float d0 = v0 - mu, d1 = v1 - mu, d2 = v2 - mu;
  float vs = d0 * d0 + d1 * d1 + d2 * d2;
#pragma unroll
  for (int off = 32; off > 0; off >>= 1) vs += __shfl_xor(vs, off);
  const float rstd = rsqrtf(vs * (1.0f / 192.0f) + 1e-5f);
  bf16* orow = out + (size_t)ridx * 192;
  orow[lane]       = __float2bfloat16(d0 * rstd * gw[lane]       + bw[lane]);
  orow[lane + 64]  = __float2bfloat16(d1 * rstd * gw[lane + 64]  + bw[lane + 64]);
  orow[lane + 128] = __float2bfloat16(d2 * rstd * gw[lane + 128] + bw[lane + 128]);
}

// ---------- GEMM: out[m,n] = sum_k A[m,k]*Bt[n,k] + bias[n], fused epilogues ----------
// A,Bt bf16; bias/resid fp32. 128x64 tile, BK=64, 4 waves 2x2, reg-staged LDS,
// T2 XOR swizzle (LDS row r byte p holds source k_bytes = p ^ ((r&7)<<4)).
// MODE 0: QKV   -> bf16 out
// MODE 1: proj  -> fp32 out at un-shifted token (+3 map, same as forward gather) + resid(x)
// MODE 2: fc1   -> bf16 out, exact GELU
// MODE 3: fc2   -> fp32 out += (in-place residual)
template<int MODE>
__global__ __launch_bounds__(256) void gemm_kernel(const bf16* __restrict__ A,
                                                   const bf16* __restrict__ Bt,
                                                   const float* __restrict__ bias,
                                                   const float* __restrict__ resid,
                                                   void* __restrict__ outv,
                                                   int N, int K, int grow0)
{
  __shared__ short lds[128 * 64 + 64 * 64];  // A[128][64] + B[64][64] bf16, 24 KiB
  short* ldsA = lds;
  short* ldsB = lds + 128 * 64;
  const int tid  = threadIdx.x;
  const int lane = tid & 63;
  const int w    = tid >> 6;
  const int wm   = (w >> 1) * 64;
  const int wn   = (w & 1) * 32;
  const int m0   = blockIdx.x * 128;
  const int n0   = blockIdx.y * 64;

  f32x4 acc[4][2];
#pragma unroll
  for (int i = 0; i < 4; i++)
#pragma unroll
    for (int j = 0; j < 2; j++) acc[i][j] = (f32x4){0.f, 0.f, 0.f, 0.f};

  const int nk = K >> 6;
  for (int kt = 0; kt < nk; kt++) {
    const int k0 = kt << 6;
    bf16x8 va[4], vb[2];
#pragma unroll
    for (int i = 0; i < 4; i++) {
      const int s = tid + 256 * i;
      const int row = s >> 3, seg = s & 7;
      va[i] = *(const bf16x8*)(A + (size_t)(m0 + row) * K + (k0 + seg * 8));
    }
#pragma unroll
    for (int i = 0; i < 2; i++) {
      const int s = tid + 256 * i;
      const int row = s >> 3, seg = s & 7;
      vb[i] = *(const bf16x8*)(Bt + (size_t)(n0 + row) * K + (k0 + seg * 8));
    }
#pragma unroll
    for (int i = 0; i < 4; i++) {
      const int s = tid + 256 * i;
      const int row = s >> 3, seg = s & 7;
      *(bf16x8*)((char*)ldsA + row * 128 + ((seg * 16) ^ ((row & 7) << 4))) = va[i];
    }
#pragma unroll
    for (int i = 0; i < 2; i++) {
      const int s = tid + 256 * i;
      const int row = s >> 3, seg = s & 7;
      *(bf16x8*)((char*)ldsB + row * 128 + ((seg * 16) ^ ((row & 7) << 4))) = vb[i];
    }
    __syncthreads();
#pragma unroll
    for (int kk = 0; kk < 2; kk++) {
      bf16x8 af[4], bg[2];
#pragma unroll
      for (int mf = 0; mf < 4; mf++) {
        const int row = wm + mf * 16 + (lane & 15);
        const int kb  = (kk * 64 + ((lane >> 4) << 4)) ^ ((row & 7) << 4);
        af[mf] = *(const bf16x8*)((const char*)ldsA + row * 128 + kb);
      }
#pragma unroll
      for (int nf = 0; nf < 2; nf++) {
        const int row = wn + nf * 16 + (lane & 15);
        const int kb  = (kk * 64 + ((lane >> 4) << 4)) ^ ((row & 7) << 4);
        bg[nf] = *(const bf16x8*)((const char*)ldsB + row * 128 + kb);
      }
#pragma unroll
      for (int mf = 0; mf < 4; mf++)
#pragma unroll
        for (int nf = 0; nf < 2; nf++)
          acc[mf][nf] = __builtin_amdgcn_mfma_f32_16x16x32_bf16(af[mf], bg[nf], acc[mf][nf], 0, 0, 0);
    }
    __syncthreads();
  }

  // epilogue: D layout col=lane&15, row=(lane>>4)*4+r  [m89-verified]
  float bv[2];
  int ncol[2];
#pragma unroll
  for (int nf = 0; nf < 2; nf++) {
    ncol[nf] = n0 + wn + nf * 16 + (lane & 15);
    bv[nf]   = bias[ncol[nf]];
  }
#pragma unroll
  for (int mf = 0; mf < 4; mf++) {
#pragma unroll
    for (int r = 0; r < 4; r++) {
      const int m = m0 + wm + mf * 16 + ((lane >> 4) << 2) + r;
      if constexpr (MODE == 1) {
        // GLOBAL window row gm (shifted coord u) scatters to token i=(u+3)%56, j=(v+3)%56
        const int gm  = grow0 + m;
        const int wid = gm / 49;
        const int nn  = gm - wid * 49;
        const int b_  = wid >> 6, wim = wid & 63;
        const int wy  = wim >> 3, wx = wim & 7;
        const int ny  = nn / 7, nx = nn - (nn / 7) * 7;
        int i = wy * 7 + ny + 3; if (i >= 56) i -= 56;
        int j = wx * 7 + nx + 3; if (j >= 56) j -= 56;
        const size_t t = (size_t)(b_ * 3136 + i * 56 + j) * 192;
        float* O = (float*)outv;
#pragma unroll
        for (int nf = 0; nf < 2; nf++)
          O[t + ncol[nf]] = acc[mf][nf][r] + bv[nf] + resid[t + ncol[nf]];
      } else if constexpr (MODE == 3) {
        float* O = (float*)outv + (size_t)m * N;
#pragma unroll
        for (int nf = 0; nf < 2; nf++)
          O[ncol[nf]] = acc[mf][nf][r] + bv[nf] + O[ncol[nf]];
      } else {
        bf16* O = (bf16*)outv + (size_t)m * N;
#pragma unroll
        for (int nf = 0; nf < 2; nf++) {
          float v = acc[mf][nf][r] + bv[nf];
          if constexpr (MODE == 2) v = 0.5f * v * (1.0f + erff(v * 0.7071067811865476f));
          O[ncol[nf]] = __float2bfloat16(v);
        }
      }
    }
  }
}

// ---------- windowed attention: one wave per (window, head); wid chunk-local ----------
__global__ __launch_bounds__(64) void attn_kernel(const bf16* __restrict__ qkv,
                                                  const float* __restrict__ rpb,
                                                  bf16* __restrict__ aout)
{
  __shared__ float Kl[49 * 32];
  __shared__ float Vl[49 * 32];
  __shared__ float Sl[49 * 49];   // stride 49 floats -> bank stride 17, conflict-free
  const int tid = threadIdx.x;
  const int wid = blockIdx.x;     // mask depends only on wid & 63 (64 windows per image)
  const int h   = blockIdx.y;
  const unsigned short* qkvu = (const unsigned short*)qkv;
  const size_t base = (size_t)wid * 49 * 576 + h * 32;

  for (int idx4 = tid; idx4 < 392; idx4 += 64) {   // 49 rows * 8 ushort4
    const int n  = idx4 >> 3;
    const int d4 = (idx4 & 7) << 2;
    const size_t rb = base + (size_t)n * 576 + d4;
    ushort4 ku = *(const ushort4*)(qkvu + rb + 192);
    ushort4 vu = *(const ushort4*)(qkvu + rb + 384);
    Kl[n*32+d4+0]=b2f(ku.x); Kl[n*32+d4+1]=b2f(ku.y); Kl[n*32+d4+2]=b2f(ku.z); Kl[n*32+d4+3]=b2f(ku.w);
    Vl[n*32+d4+0]=b2f(vu.x); Vl[n*32+d4+1]=b2f(vu.y); Vl[n*32+d4+2]=b2f(vu.z); Vl[n*32+d4+3]=b2f(vu.w);
  }
  float q[32];
  const int m = tid;
  if (m < 49) {
    const ushort4* qp = (const ushort4*)(qkvu + base + (size_t)m * 576);
#pragma unroll
    for (int i = 0; i < 8; i++) {
      ushort4 u = qp[i];
      q[4*i+0]=b2f(u.x)*0.1767766953f; q[4*i+1]=b2f(u.y)*0.1767766953f;
      q[4*i+2]=b2f(u.z)*0.1767766953f; q[4*i+3]=b2f(u.w)*0.1767766953f;
    }
  }
  __syncthreads();
  if (m < 49) {
    const int wim = wid & 63;
    const int wy = wim >> 3, wx = wim & 7;
    const int mh = m / 7, mw = m - mh * 7;
    const int labm = reg3(wy * 7 + mh) * 3 + reg3(wx * 7 + mw);
    float rmax = -3e38f;
    int nh_ = 0, nw_ = 0;
    for (int n = 0; n < 49; n++) {
      float s = 0.f;
#pragma unroll
      for (int d = 0; d < 32; d++) s += q[d] * Kl[n * 32 + d];
      s += rpb[((mh - nh_ + 6) * 13 + (mw - nw_ + 6)) * 6 + h];   // REL_IDX bias
      const int labn = reg3(wy * 7 + nh_) * 3 + reg3(wx * 7 + nw_);
      if (labn != labm) s -= 100.f;                               // shift mask
      Sl[m * 49 + n] = s;
      rmax = fmaxf(rmax, s);
      if (++nw_ == 7) { nw_ = 0; nh_++; }
    }
    float ssum = 0.f;
    for (int n = 0; n < 49; n++) {
      float p = __expf(Sl[m * 49 + n] - rmax);
      ssum += p;
      Sl[m * 49 + n] = p;
    }
    float oa[32];
#pragma unroll
    for (int d = 0; d < 32; d++) oa[d] = 0.f;
    for (int n = 0; n < 49; n++) {
      const float p = Sl[m * 49 + n];
#pragma unroll
      for (int d = 0; d < 32; d++) oa[d] += p * Vl[n * 32 + d];
    }
    const float inv = 1.0f / ssum;
    bf16* orow = aout + (size_t)(wid * 49 + m) * 192 + h * 32;
#pragma unroll
    for (int d = 0; d < 32; d++) orow[d] = __float2bfloat16(oa[d] * inv);
  }
}

extern "C" void kernel_launch(void* const* d_in, const int* in_sizes, int n_in,
                              void* d_out, int out_size, void* d_ws, size_t ws_size,
                              hipStream_t stream)
{
  (void)in_sizes; (void)n_in; (void)out_size;
  const float* x     = (const float*)d_in[0];
  const float* ln1g  = (const float*)d_in[1];
  const float* ln1b  = (const float*)d_in[2];
  const float* qkvw  = (const float*)d_in[3];
  const float* qkvb  = (const float*)d_in[4];
  const float* projw = (const float*)d_in[5];
  const float* projb = (const float*)d_in[6];
  const float* rpb   = (const float*)d_in[7];
  const float* ln2g  = (const float*)d_in[8];
  const float* ln2b  = (const float*)d_in[9];
  const float* fc1w  = (const float*)d_in[10];
  const float* fc1b  = (const float*)d_in[11];
  const float* fc2w  = (const float*)d_in[12];
  const float* fc2b  = (const float*)d_in[13];
  float* out = (float*)d_out;
  char* ws   = (char*)d_ws;

  // ---- bf16 weight copies at head of ws (884736 B total) ----
  bf16* wqkv = (bf16*)(ws);              // 110592 el
  bf16* wproj = (bf16*)(ws + 221184);    //  36864 el
  bf16* wfc1 = (bf16*)(ws + 294912);     // 147456 el
  bf16* wfc2 = (bf16*)(ws + 589824);     // 147456 el
  cvt_kernel<<<dim3(432), dim3(256), 0, stream>>>(qkvw, wqkv, 110592);
  cvt_kernel<<<dim3(144), dim3(256), 0, stream>>>(projw, wproj, 36864);
  cvt_kernel<<<dim3(576), dim3(256), 0, stream>>>(fc1w, wfc1, 147456);
  cvt_kernel<<<dim3(576), dim3(256), 0, stream>>>(fc2w, wfc2, 147456);

  char* cws = ws + 884736;
  const size_t avail = (ws_size > 884736ull) ? ws_size - 884736ull : 0;

  // ---- attention pipeline, chunked over batch (permutes are batch-local) ----
  // per chunk bytes: qkv_c = Bc*3612672 ; hwin_c (also attnout) = Bc*1204224
  int Bc = 32;
  while (Bc > 2 && (size_t)Bc * 4816896ull > avail) Bc >>= 1;
  const int nb = 32 / Bc;
  bf16* qkv_c  = (bf16*)cws;
  bf16* hwin_c = (bf16*)(cws + (size_t)Bc * 3612672ull);

  for (int c = 0; c < nb; c++) {
    const int R0 = c * Bc * 3136;       // global window-row offset
    const int Mc = Bc * 3136;
    ln_kernel<true><<<dim3(Mc / 4), dim3(256), 0, stream>>>(x, ln1g, ln1b, hwin_c, R0);
    gemm_kernel<0><<<dim3(Mc / 128, 9), dim3(256), 0, stream>>>(hwin_c, wqkv, qkvb, nullptr, qkv_c, 576, 192, 0);
    attn_kernel<<<dim3(Bc * 64, 6), dim3(64), 0, stream>>>(qkv_c, rpb, hwin_c);
    gemm_kernel<1><<<dim3(Mc / 128, 3), dim3(256), 0, stream>>>(hwin_c, wproj, projb, x, out, 192, 192, R0);
  }

  // ---- MLP, chunked over rows: ln2_c = 384*Rc B ; a1_c = 1536*Rc B ----
  int Rc = 100352;
  while (Rc > 6272 && (size_t)Rc * 1920ull > avail) Rc >>= 1;
  bf16* ln2_c = (bf16*)cws;
  bf16* a1_c  = (bf16*)(cws + (size_t)Rc * 384ull);

  for (int r0 = 0; r0 < 100352; r0 += Rc) {
    ln_kernel<false><<<dim3(Rc / 4), dim3(256), 0, stream>>>(out + (size_t)r0 * 192, ln2g, ln2b, ln2_c, 0);
    gemm_kernel<2><<<dim3(Rc / 128, 12), dim3(256), 0, stream>>>(ln2_c, wfc1, fc1b, nullptr, a1_c, 768, 192, 0);
    gemm_kernel<3><<<dim3(Rc / 128, 3), dim3(256), 0, stream>>>(a1_c, wfc2, fc2b, nullptr, out + (size_t)r0 * 192, 192, 768, 0);
  }
}

// Round 5
// 519.592 us; speedup vs baseline: 1.0132x; 1.0132x over previous
//
#include <hip/hip_runtime.h>
#include <hip/hip_bf16.h>
#include <cstdint>
#include <cstddef>

typedef __hip_bfloat16 bf16;
using f32x4  = __attribute__((ext_vector_type(4))) float;
using bf16x8 = __attribute__((ext_vector_type(8))) short;

#define DEVI __device__ __forceinline__

DEVI float b2f(unsigned short u) {
  union { float f; unsigned int i; } c; c.i = ((unsigned int)u) << 16; return c.f;
}

DEVI int reg3(int u) { return (u < 49) ? 0 : ((u < 53) ? 1 : 2); }

// async global->LDS, 16B per lane; dest = ldsbase + lane*16 (linear, wave-uniform base)
DEVI void gload_lds16(const void* g, void* l) {
  __builtin_amdgcn_global_load_lds(
      (const __attribute__((address_space(1))) unsigned int*)g,
      (__attribute__((address_space(3))) unsigned int*)l, 16, 0, 0);
}

// ---------- fp32 -> bf16 weight conversion ----------
__global__ __launch_bounds__(256) void cvt_kernel(const float* __restrict__ src,
                                                  bf16* __restrict__ dst, int n)
{
  const int i = blockIdx.x * 256 + threadIdx.x;
  if (i < n) dst[i] = __float2bfloat16(src[i]);
}

// ---------- LayerNorm over C=192 (fp32 in, bf16 out), optional shift+window gather ----------
template<bool PERM>
__global__ __launch_bounds__(256) void ln_kernel(const float* __restrict__ x,
                                                 const float* __restrict__ gw,
                                                 const float* __restrict__ bw,
                                                 bf16* __restrict__ out,
                                                 int grow0)
{
  const int lane = threadIdx.x & 63;
  const int ridx = blockIdx.x * 4 + (threadIdx.x >> 6);
  size_t src;
  if (PERM) {
    const int g   = grow0 + ridx;
    const int wid = g / 49;
    const int nn  = g - wid * 49;
    const int b_  = wid >> 6, wim = wid & 63;
    const int wy  = wim >> 3, wx = wim & 7;
    const int ny  = nn / 7,  nx = nn - (nn / 7) * 7;
    int i = wy * 7 + ny + 3; if (i >= 56) i -= 56;   // shifted coord u reads x[(u+3)%56]
    int j = wx * 7 + nx + 3; if (j >= 56) j -= 56;
    src = (size_t)(b_ * 3136 + i * 56 + j);
  } else {
    src = (size_t)ridx;
  }
  const float* xr = x + src * 192;
  float v0 = xr[lane];
  float v1 = xr[lane + 64];
  float v2 = xr[lane + 128];
  float s = v0 + v1 + v2;
#pragma unroll
  for (int off = 32; off > 0; off >>= 1) s += __shfl_xor(s, off);
  const float mu = s * (1.0f / 192.0f);
  const float d0 = v0 - mu, d1 = v1 - mu, d2 = v2 - mu;
  float vs = d0 * d0 + d1 * d1 + d2 * d2;
#pragma unroll
  for (int off = 32; off > 0; off >>= 1) vs += __shfl_xor(vs, off);
  const float rstd = rsqrtf(vs * (1.0f / 192.0f) + 1e-5f);
  bf16* orow = out + (size_t)ridx * 192;
  orow[lane]       = __float2bfloat16(d0 * rstd * gw[lane]       + bw[lane]);
  orow[lane + 64]  = __float2bfloat16(d1 * rstd * gw[lane + 64]  + bw[lane + 64]);
  orow[lane + 128] = __float2bfloat16(d2 * rstd * gw[lane + 128] + bw[lane + 128]);
}

// ---------- GEMM: out[m,n] = sum_k A[m,k]*Bt[n,k] + bias[n], fused epilogues ----------
// A,Bt bf16; bias/resid fp32. 128x64 tile, BK=64, 4 waves 2x2.
// Staging: global_load_lds w16, LINEAR LDS dest + pre-swizzled global source (rule #21):
//   LDS[row][byte p] = src[row][byte p ^ ((row&7)<<4)]  (involution; read side XORs same).
// Grid: blockIdx.x = n-block (fastest) so concurrent blocks share one A-panel in L2.
// MODE 0: QKV -> bf16 | 1: proj -> fp32 @ un-shifted token + resid | 2: fc1 bf16+GELU | 3: fc2 fp32 +=
template<int MODE>
__global__ __launch_bounds__(256) void gemm_kernel(const bf16* __restrict__ A,
                                                   const bf16* __restrict__ Bt,
                                                   const float* __restrict__ bias,
                                                   const float* __restrict__ resid,
                                                   void* __restrict__ outv,
                                                   int N, int K, int grow0)
{
  __shared__ short lds[128 * 64 + 64 * 64];  // A[128][64] + B[64][64] bf16, 24 KiB
  short* ldsA = lds;
  short* ldsB = lds + 128 * 64;
  const int tid  = threadIdx.x;
  const int lane = tid & 63;
  const int w    = tid >> 6;
  const int wm   = (w >> 1) * 64;
  const int wn   = (w & 1) * 32;
  const int m0   = blockIdx.y * 128;
  const int n0   = blockIdx.x * 64;
  const int lrow = lane >> 3;          // 0..7 row within 8-row chunk
  const int lseg = lane & 7;           // 0..7 16B-segment within row
  const int ksw  = (lseg * 8) ^ (lrow << 3);   // pre-swizzled source k (elements)

  f32x4 acc[4][2];
#pragma unroll
  for (int i = 0; i < 4; i++)
#pragma unroll
    for (int j = 0; j < 2; j++) acc[i][j] = (f32x4){0.f, 0.f, 0.f, 0.f};

  const int nk = K >> 6;
  for (int kt = 0; kt < nk; kt++) {
    const int k0 = kt << 6;
    // A tile 16KB: 16 x 1KB instrs (8 rows each); wave w covers chunks w*4..w*4+3
#pragma unroll
    for (int i = 0; i < 4; i++) {
      const int chunk = w * 4 + i;
      gload_lds16(A + (size_t)(m0 + chunk * 8 + lrow) * K + (k0 + ksw), ldsA + chunk * 512);
    }
#pragma unroll
    for (int i = 0; i < 2; i++) {
      const int chunk = w * 2 + i;
      gload_lds16(Bt + (size_t)(n0 + chunk * 8 + lrow) * K + (k0 + ksw), ldsB + chunk * 512);
    }
    __syncthreads();   // compiler drains vmcnt(0) before s_barrier
#pragma unroll
    for (int kk = 0; kk < 2; kk++) {
      bf16x8 af[4], bg[2];
#pragma unroll
      for (int mf = 0; mf < 4; mf++) {
        const int row = wm + mf * 16 + (lane & 15);
        const int kb  = (kk * 64 + ((lane >> 4) << 4)) ^ ((row & 7) << 4);
        af[mf] = *(const bf16x8*)((const char*)ldsA + row * 128 + kb);
      }
#pragma unroll
      for (int nf = 0; nf < 2; nf++) {
        const int row = wn + nf * 16 + (lane & 15);
        const int kb  = (kk * 64 + ((lane >> 4) << 4)) ^ ((row & 7) << 4);
        bg[nf] = *(const bf16x8*)((const char*)ldsB + row * 128 + kb);
      }
#pragma unroll
      for (int mf = 0; mf < 4; mf++)
#pragma unroll
        for (int nf = 0; nf < 2; nf++)
          acc[mf][nf] = __builtin_amdgcn_mfma_f32_16x16x32_bf16(af[mf], bg[nf], acc[mf][nf], 0, 0, 0);
    }
    __syncthreads();
  }

  // epilogue: D layout col=lane&15, row=(lane>>4)*4+r  [m89-verified]
  float bv[2];
  int ncol[2];
#pragma unroll
  for (int nf = 0; nf < 2; nf++) {
    ncol[nf] = n0 + wn + nf * 16 + (lane & 15);
    bv[nf]   = bias[ncol[nf]];
  }
#pragma unroll
  for (int mf = 0; mf < 4; mf++) {
#pragma unroll
    for (int r = 0; r < 4; r++) {
      const int m = m0 + wm + mf * 16 + ((lane >> 4) << 2) + r;
      if constexpr (MODE == 1) {
        // GLOBAL window row gm (shifted coord u) scatters to token i=(u+3)%56, j=(v+3)%56
        const int gm  = grow0 + m;
        const int wid = gm / 49;
        const int nn  = gm - wid * 49;
        const int b_  = wid >> 6, wim = wid & 63;
        const int wy  = wim >> 3, wx = wim & 7;
        const int ny  = nn / 7, nx = nn - (nn / 7) * 7;
        int i = wy * 7 + ny + 3; if (i >= 56) i -= 56;
        int j = wx * 7 + nx + 3; if (j >= 56) j -= 56;
        const size_t t = (size_t)(b_ * 3136 + i * 56 + j) * 192;
        float* O = (float*)outv;
#pragma unroll
        for (int nf = 0; nf < 2; nf++)
          O[t + ncol[nf]] = acc[mf][nf][r] + bv[nf] + resid[t + ncol[nf]];
      } else if constexpr (MODE == 3) {
        float* O = (float*)outv + (size_t)m * N;
#pragma unroll
        for (int nf = 0; nf < 2; nf++)
          O[ncol[nf]] = acc[mf][nf][r] + bv[nf] + O[ncol[nf]];
      } else {
        bf16* O = (bf16*)outv + (size_t)m * N;
#pragma unroll
        for (int nf = 0; nf < 2; nf++) {
          float v = acc[mf][nf][r] + bv[nf];
          if constexpr (MODE == 2) v = 0.5f * v * (1.0f + erff(v * 0.7071067811865476f));
          O[ncol[nf]] = __float2bfloat16(v);
        }
      }
    }
  }
}

// ---------- windowed attention: one wave per (window, head); wid chunk-local ----------
// R4: 4-way ILP partial sums in QK dot, fused exp+PV pass, rpb head-slice in LDS,
//     precomputed 49-bit disallow mask. Semantics identical to R3 (passing).
__global__ __launch_bounds__(64) void attn_kernel(const bf16* __restrict__ qkv,
                                                  const float* __restrict__ rpb,
                                                  bf16* __restrict__ aout)
{
  __shared__ float Kl[49 * 32];
  __shared__ float Vl[49 * 32];
  __shared__ float Sl[49 * 49];   // stride 49 floats -> bank stride 17, conflict-free
  __shared__ float rpbl[169];
  const int tid = threadIdx.x;
  const int wid = blockIdx.x;     // mask depends only on wid & 63 (64 windows per image)
  const int h   = blockIdx.y;
  const unsigned short* qkvu = (const unsigned short*)qkv;
  const size_t base = (size_t)wid * 49 * 576 + h * 32;

  for (int i = tid; i < 169; i += 64) rpbl[i] = rpb[i * 6 + h];
  for (int idx4 = tid; idx4 < 392; idx4 += 64) {   // 49 rows * 8 ushort4
    const int n  = idx4 >> 3;
    const int d4 = (idx4 & 7) << 2;
    const size_t rb = base + (size_t)n * 576 + d4;
    ushort4 ku = *(const ushort4*)(qkvu + rb + 192);
    ushort4 vu = *(const ushort4*)(qkvu + rb + 384);
    Kl[n*32+d4+0]=b2f(ku.x); Kl[n*32+d4+1]=b2f(ku.y); Kl[n*32+d4+2]=b2f(ku.z); Kl[n*32+d4+3]=b2f(ku.w);
    Vl[n*32+d4+0]=b2f(vu.x); Vl[n*32+d4+1]=b2f(vu.y); Vl[n*32+d4+2]=b2f(vu.z); Vl[n*32+d4+3]=b2f(vu.w);
  }
  float q[32];
  const int m = tid;
  if (m < 49) {
    const ushort4* qp = (const ushort4*)(qkvu + base + (size_t)m * 576);
#pragma unroll
    for (int i = 0; i < 8; i++) {
      ushort4 u = qp[i];
      q[4*i+0]=b2f(u.x)*0.1767766953f; q[4*i+1]=b2f(u.y)*0.1767766953f;
      q[4*i+2]=b2f(u.z)*0.1767766953f; q[4*i+3]=b2f(u.w)*0.1767766953f;
    }
  }
  __syncthreads();
  if (m < 49) {
    const int wim = wid & 63;
    const int wy = wim >> 3, wx = wim & 7;
    const int mh = m / 7, mw = m - mh * 7;
    const int labm = reg3(wy * 7 + mh) * 3 + reg3(wx * 7 + mw);
    // 49-bit disallow mask (labn != labm)
    unsigned long long bad = 0ull;
    {
      int nh_ = 0, nw_ = 0;
      for (int n = 0; n < 49; n++) {
        const int labn = reg3(wy * 7 + nh_) * 3 + reg3(wx * 7 + nw_);
        if (labn != labm) bad |= (1ull << n);
        if (++nw_ == 7) { nw_ = 0; nh_++; }
      }
    }
    float rmax = -3e38f;
    int nh_ = 0, nw_ = 0;
    for (int n = 0; n < 49; n++) {
      const float* kp = &Kl[n * 32];
      float t0 = 0.f, t1 = 0.f, t2 = 0.f, t3 = 0.f;   // 4-way ILP
#pragma unroll
      for (int d = 0; d < 32; d += 4) {
        t0 += q[d]     * kp[d];
        t1 += q[d + 1] * kp[d + 1];
        t2 += q[d + 2] * kp[d + 2];
        t3 += q[d + 3] * kp[d + 3];
      }
      float s = (t0 + t1) + (t2 + t3);
      s += rpbl[(mh - nh_ + 6) * 13 + (mw - nw_ + 6)];
      if (bad & (1ull << n)) s -= 100.f;
      Sl[m * 49 + n] = s;
      rmax = fmaxf(rmax, s);
      if (++nw_ == 7) { nw_ = 0; nh_++; }
    }
    float ssum = 0.f;
    float oa[32];
#pragma unroll
    for (int d = 0; d < 32; d++) oa[d] = 0.f;
    for (int n = 0; n < 49; n++) {       // fused exp + PV
      const float p = __expf(Sl[m * 49 + n] - rmax);
      ssum += p;
      const float* vp = &Vl[n * 32];
#pragma unroll
      for (int d = 0; d < 32; d++) oa[d] += p * vp[d];
    }
    const float inv = 1.0f / ssum;
    bf16* orow = aout + (size_t)(wid * 49 + m) * 192 + h * 32;
#pragma unroll
    for (int d = 0; d < 32; d++) orow[d] = __float2bfloat16(oa[d] * inv);
  }
}

extern "C" void kernel_launch(void* const* d_in, const int* in_sizes, int n_in,
                              void* d_out, int out_size, void* d_ws, size_t ws_size,
                              hipStream_t stream)
{
  (void)in_sizes; (void)n_in; (void)out_size;
  const float* x     = (const float*)d_in[0];
  const float* ln1g  = (const float*)d_in[1];
  const float* ln1b  = (const float*)d_in[2];
  const float* qkvw  = (const float*)d_in[3];
  const float* qkvb  = (const float*)d_in[4];
  const float* projw = (const float*)d_in[5];
  const float* projb = (const float*)d_in[6];
  const float* rpb   = (const float*)d_in[7];
  const float* ln2g  = (const float*)d_in[8];
  const float* ln2b  = (const float*)d_in[9];
  const float* fc1w  = (const float*)d_in[10];
  const float* fc1b  = (const float*)d_in[11];
  const float* fc2w  = (const float*)d_in[12];
  const float* fc2b  = (const float*)d_in[13];
  float* out = (float*)d_out;
  char* ws   = (char*)d_ws;

  // ---- bf16 weight copies at head of ws (884736 B total) ----
  bf16* wqkv = (bf16*)(ws);              // 110592 el
  bf16* wproj = (bf16*)(ws + 221184);    //  36864 el
  bf16* wfc1 = (bf16*)(ws + 294912);     // 147456 el
  bf16* wfc2 = (bf16*)(ws + 589824);     // 147456 el
  cvt_kernel<<<dim3(432), dim3(256), 0, stream>>>(qkvw, wqkv, 110592);
  cvt_kernel<<<dim3(144), dim3(256), 0, stream>>>(projw, wproj, 36864);
  cvt_kernel<<<dim3(576), dim3(256), 0, stream>>>(fc1w, wfc1, 147456);
  cvt_kernel<<<dim3(576), dim3(256), 0, stream>>>(fc2w, wfc2, 147456);

  char* cws = ws + 884736;
  const size_t avail = (ws_size > 884736ull) ? ws_size - 884736ull : 0;

  // ---- attention pipeline, chunked over batch (permutes are batch-local) ----
  // per chunk bytes: qkv_c = Bc*3612672 ; hwin_c (also attnout) = Bc*1204224
  int Bc = 32;
  while (Bc > 2 && (size_t)Bc * 4816896ull > avail) Bc >>= 1;
  const int nb = 32 / Bc;
  bf16* qkv_c  = (bf16*)cws;
  bf16* hwin_c = (bf16*)(cws + (size_t)Bc * 3612672ull);

  for (int c = 0; c < nb; c++) {
    const int R0 = c * Bc * 3136;       // global window-row offset
    const int Mc = Bc * 3136;
    ln_kernel<true><<<dim3(Mc / 4), dim3(256), 0, stream>>>(x, ln1g, ln1b, hwin_c, R0);
    gemm_kernel<0><<<dim3(9, Mc / 128), dim3(256), 0, stream>>>(hwin_c, wqkv, qkvb, nullptr, qkv_c, 576, 192, 0);
    attn_kernel<<<dim3(Bc * 64, 6), dim3(64), 0, stream>>>(qkv_c, rpb, hwin_c);
    gemm_kernel<1><<<dim3(3, Mc / 128), dim3(256), 0, stream>>>(hwin_c, wproj, projb, x, out, 192, 192, R0);
  }

  // ---- MLP, chunked over rows: ln2_c = 384*Rc B ; a1_c = 1536*Rc B ----
  int Rc = 100352;
  while (Rc > 6272 && (size_t)Rc * 1920ull > avail) Rc >>= 1;
  bf16* ln2_c = (bf16*)cws;
  bf16* a1_c  = (bf16*)(cws + (size_t)Rc * 384ull);

  for (int r0 = 0; r0 < 100352; r0 += Rc) {
    ln_kernel<false><<<dim3(Rc / 4), dim3(256), 0, stream>>>(out + (size_t)r0 * 192, ln2g, ln2b, ln2_c, 0);
    gemm_kernel<2><<<dim3(12, Rc / 128), dim3(256), 0, stream>>>(ln2_c, wfc1, fc1b, nullptr, a1_c, 768, 192, 0);
    gemm_kernel<3><<<dim3(3, Rc / 128), dim3(256), 0, stream>>>(a1_c, wfc2, fc2b, nullptr, out + (size_t)r0 * 192, 192, 768, 0);
  }
}